// Round 5
// baseline (194.944 us; speedup 1.0000x reference)
//
#include <hip/hip_runtime.h>

// LinearAttention (Performer/FAVOR+): B=8, T=S=8192, F=D=64, M=128 (2M=256 features)
// R11: R10's 92us kv_fused was SCRATCH SPILL: bounds(256,4) caps 128 VGPR, acc[4][5]
// (80 VGPR) live across the sc loop spilled -> VGPR_Count=64, WRITE 115.7MB vs 18.9MB
// partial, FETCH 85MB vs 34MB. Steady-state accounting: dur ~= 83us fills (2x256MiB,
// harness-fixed) + kv + fin(3.3) + qkv(6) + overhead(~7). R8's kv ~= 27us @ 2 blk/CU.
// Fix: split M across blocks, not more work per block:
//   grid 1024 = 8b x 64 superchunks(128 s) x 2 m-halves (mh=0:+feat, mh=1:-feat).
//   Wave owns 2 omega tiles, ONE sign -> acc[2][5]=40 VGPR (no spill at 128 cap),
//   LDS 18.4KB, partial stays 18.9MB (128 m-rows/block). 4 blk/CU = 2x occupancy.
//   Cost: K/V read 2x (L3-resident, inputs 50MB < 256MB L3) + phi-MFMA 2x (~3us).
// Predicted: kv 10-16us, VGPR>=96, WRITE~19MB, total 112-122us.
//
// MFMA 16x16x32 bf16 layouts (measured, learn_hip m89/m91):
//   A-frag: lane holds A[m = lane&15][k = (lane>>4)*8 + j], j=0..7
//   B-frag: lane holds B[k = (lane>>4)*8 + j][n = lane&15]
//   C/D   : lane holds D[row = (lane>>4)*4 + reg][col = lane&15], reg=0..3

constexpr int NB = 8;
constexpr int NT = 8192;
constexpr float EPSF = 1e-9f;
constexpr float SCALE = 0.0625f;  // 1/sqrt(2*128)

typedef short s8v __attribute__((ext_vector_type(8)));
typedef short s4v __attribute__((ext_vector_type(4)));
typedef float f4v __attribute__((ext_vector_type(4)));

__device__ inline f4v mfma16(s8v a, s8v b, f4v c) {
  return __builtin_amdgcn_mfma_f32_16x16x32_bf16(a, b, c, 0, 0, 0);
}

__device__ inline short bf16_rne(float f) {
  unsigned u = __builtin_bit_cast(unsigned, f);
  u += 0x7fffu + ((u >> 16) & 1u);
  return (short)(u >> 16);
}
__device__ inline float bf16_to_f(short h) {
  unsigned u = ((unsigned)(unsigned short)h) << 16;
  return __builtin_bit_cast(float, u);
}

// ---- setup: split omega into bf16 hi/lo (Markidis 3-term split), stored in
// MFMA-FRAG ORDER: ohf[((ft*2 + h)*64 + lane)*8 + jj] = omega_hi[m][f] with
// m = ft*16 + (lane&15), f = h*32 + (lane>>4)*8 + jj. ----
__global__ void setup_omega(const float* __restrict__ omega,
                            short* __restrict__ ohf, short* __restrict__ olf) {
  int i = blockIdx.x * 256 + threadIdx.x;
  if (i >= 128 * 64) return;
  int jj = i & 7;
  int lane = (i >> 3) & 63;
  int h = (i >> 9) & 1;
  int ft = i >> 10;
  int m = ft * 16 + (lane & 15);
  int f = h * 32 + (lane >> 4) * 8 + jj;
  float wv = omega[m * 64 + f];
  short hh = bf16_rne(wv);
  ohf[i] = hh;
  olf[i] = bf16_rne(wv - bf16_to_f(hh));
}

// ---- shared phi helpers ----
struct PhiRows {
  s8v ah0, al0, ah1, al1;  // x fragments (hi/lo) for ksteps 0,1
  float ssr[4];            // |x_row|^2/2 for rows quad*4+reg (C-row indexed)
  float ss;                // |x_row|^2/2 for this lane's own row (lane&15)
};

__device__ inline void split8(f4v a, f4v b, s8v& h, s8v& l) {
  float v[8] = {a.x, a.y, a.z, a.w, b.x, b.y, b.z, b.w};
#pragma unroll
  for (int j = 0; j < 8; ++j) {
    short hh = bf16_rne(v[j]);
    h[j] = hh;
    l[j] = bf16_rne(v[j] - bf16_to_f(hh));
  }
}

__device__ inline void load_phi_rows(const float* __restrict__ xrow_base, int lane, PhiRows& P) {
  const int r = lane & 15, q = lane >> 4;
  const float* p = xrow_base + r * 64 + q * 8;
  f4v u0 = *(const f4v*)(p);
  f4v u1 = *(const f4v*)(p + 4);
  f4v u2 = *(const f4v*)(p + 32);
  f4v u3 = *(const f4v*)(p + 36);
  float ss = u0.x * u0.x + u0.y * u0.y + u0.z * u0.z + u0.w * u0.w
           + u1.x * u1.x + u1.y * u1.y + u1.z * u1.z + u1.w * u1.w
           + u2.x * u2.x + u2.y * u2.y + u2.z * u2.z + u2.w * u2.w
           + u3.x * u3.x + u3.y * u3.y + u3.z * u3.z + u3.w * u3.w;
  ss += __shfl_xor(ss, 16, 64);
  ss += __shfl_xor(ss, 32, 64);
  ss *= 0.5f;
  P.ss = ss;
#pragma unroll
  for (int reg = 0; reg < 4; ++reg) P.ssr[reg] = __shfl(ss, q * 4 + reg, 64);
  split8(u0, u1, P.ah0, P.al0);
  split8(u2, u3, P.ah1, P.al1);
}

// xw C-tile, A = x rows (C: row = x-row q*4+reg, col = omega-row lane&15).
__device__ inline f4v phi_xw_tile(const PhiRows& P, const short* __restrict__ ohf,
                                  const short* __restrict__ olf, int ft, int lane) {
  const int o0 = ft * 1024 + lane * 8;
  s8v bh0 = *(const s8v*)(ohf + o0);
  s8v bh1 = *(const s8v*)(ohf + o0 + 512);
  s8v bl0 = *(const s8v*)(olf + o0);
  s8v bl1 = *(const s8v*)(olf + o0 + 512);
  f4v c = {0.f, 0.f, 0.f, 0.f};
  c = mfma16(P.ah0, bh0, c);
  c = mfma16(P.ah1, bh1, c);
  c = mfma16(P.al0, bh0, c);
  c = mfma16(P.al1, bh1, c);
  c = mfma16(P.ah0, bl0, c);
  c = mfma16(P.ah1, bl1, c);
  return c;
}

// xw C-tile, swapped: A = omega rows (C: row = omega-row q*4+reg, col = x-row lane&15).
__device__ inline f4v phi_xw_tile_T(const PhiRows& P, const short* __restrict__ ohf,
                                    const short* __restrict__ olf, int ft, int lane) {
  const int o0 = ft * 1024 + lane * 8;
  s8v ah0 = *(const s8v*)(ohf + o0);
  s8v ah1 = *(const s8v*)(ohf + o0 + 512);
  s8v al0 = *(const s8v*)(olf + o0);
  s8v al1 = *(const s8v*)(olf + o0 + 512);
  f4v c = {0.f, 0.f, 0.f, 0.f};
  c = mfma16(ah0, P.ah0, c);
  c = mfma16(ah1, P.ah1, c);
  c = mfma16(al0, P.ah0, c);
  c = mfma16(al1, P.ah1, c);
  c = mfma16(ah0, P.al0, c);
  c = mfma16(ah1, P.al1, c);
  return c;
}

constexpr int KF_P = 72;                 // kft pitch in shorts (also partial row pitch)
constexpr int QF_P = 264;                // qf pitch (shorts): 256 + 8 pad
constexpr int PART_P = 72;               // partial pitch per m-row
constexpr int PART_ROWS = 128;           // m-rows per kv block (one m-half)
constexpr int PART_SZ = PART_ROWS * PART_P;  // 9216 shorts per block tile
constexpr int ACC_SZ = 256 * PART_P;     // kvacc fallback tile (floats)
constexpr int KV_GRID = 1024;            // 8b x 64 superchunks(128 s) x 2 m-halves

// ---- Kernel KV: fused phi(k) + kv GEMM; m-split blocks, no spill, 4 blk/CU ----
// blockIdx: b = blk>>7; scb = (blk&127)>>1; mh = blk&1 (0:+feat, 1:-feat).
// Wave w owns omega tiles {2w, 2w+1}, sign mh -> 32 m-rows, acc[2][5]=40 VGPR.
// Wave-private kft quarter [32 m][72 s]; zero barriers.
__global__ __launch_bounds__(256, 4) void kv_fused(
    const float* __restrict__ key, const float* __restrict__ value,
    const short* __restrict__ ohf, const short* __restrict__ olf,
    short* __restrict__ partial, float* __restrict__ kvacc, int use_partial) {
  __shared__ short kft[4 * 32 * KF_P];  // 18432 B, wave-private quarters
  const int tid = threadIdx.x, lane = tid & 63, w = tid >> 6;
  const int b = blockIdx.x >> 7;
  const int rem = blockIdx.x & 127;
  const int scb = rem >> 1, mh = rem & 1;
  const int s00 = scb * 128;
  const int q = lane >> 4, r15 = lane & 15;
  short* kw = kft + w * 32 * KF_P;

  // constant [v|1] ones-column fragment: B[k][n=64..79] = (n==64) ? 1.0 : 0
  s8v vone;
#pragma unroll
  for (int jj = 0; jj < 8; ++jj) vone[jj] = (r15 == 0) ? (short)0x3F80 : (short)0;

  f4v acc[2][5];
#pragma unroll
  for (int mt = 0; mt < 2; ++mt)
#pragma unroll
    for (int n = 0; n < 5; ++n) acc[mt][n] = f4v{0.f, 0.f, 0.f, 0.f};

  for (int sc = 0; sc < 2; ++sc) {
    const int s0 = s00 + sc * 64;
    // phi(k): 4 row-groups of 16 s; this wave's 2 omega tiles, sign mh.
    // (partial unroll 2: bounded key-load transients under the 128-VGPR cap)
#pragma unroll 2
    for (int rg = 0; rg < 4; ++rg) {
      PhiRows P;
      load_phi_rows(key + ((size_t)b * NT + s0 + rg * 16) * 64, lane, P);
#pragma unroll
      for (int tl = 0; tl < 2; ++tl) {
        f4v c = phi_xw_tile(P, ohf, olf, w * 2 + tl, lane);
        s4v pk;
#pragma unroll
        for (int reg = 0; reg < 4; ++reg) {
          float xw = c[reg];  // x-row (rg*16+q*4+reg), omega-row (w*2+tl)*16+r15
          float arg = mh ? (-xw - P.ssr[reg]) : (xw - P.ssr[reg]);
          pk[reg] = bf16_rne((__expf(arg) + EPSF) * SCALE);
        }
        // kft row = m_loc (tl*16+r15); col = s-local. s4v spans 4 consecutive s.
        *(s4v*)(kw + (tl * 16 + r15) * KF_P + rg * 16 + q * 4) = pk;
      }
    }
    // GEMM over this chunk's 64 s; B-frags from global value (L1/L2-resident)
    const float* vb = value + ((size_t)b * NT + s0) * 64;
#pragma unroll
    for (int ks = 0; ks < 2; ++ks) {
      s8v bf[5];
#pragma unroll
      for (int n = 0; n < 4; ++n) {
#pragma unroll
        for (int jj = 0; jj < 8; ++jj)
          bf[n][jj] = bf16_rne(vb[(ks * 32 + q * 8 + jj) * 64 + n * 16 + r15]);
      }
      bf[4] = vone;
#pragma unroll
      for (int mt = 0; mt < 2; ++mt) {
        s8v a = *(const s8v*)(kw + (mt * 16 + r15) * KF_P + ks * 32 + q * 8);
#pragma unroll
        for (int n = 0; n < 5; ++n) acc[mt][n] = mfma16(a, bf[n], acc[mt][n]);
      }
    }
  }
  // ---- epilogue ----
  // C element (mt,n,reg): m_loc = mt*16+q*4+reg (0..31), d = n*16+r15.
  if (use_partial) {
    // Stage 32x65 tile into idle kw quarter [m_loc][d] pitch 72, then
    // linear-copy 576 s4v (8B, fully coalesced 512B/wave-inst).
#pragma unroll
    for (int mt = 0; mt < 2; ++mt) {
#pragma unroll
      for (int n = 0; n < 4; ++n) {
#pragma unroll
        for (int reg = 0; reg < 4; ++reg)
          kw[(mt * 16 + q * 4 + reg) * KF_P + n * 16 + r15] = bf16_rne(acc[mt][n][reg]);
      }
      if (r15 == 0) {  // n=4 tile: only d=64 is real
#pragma unroll
        for (int reg = 0; reg < 4; ++reg)
          kw[(mt * 16 + q * 4 + reg) * KF_P + 64] = bf16_rne(acc[mt][4][reg]);
      }
    }
    // partial[block][pr=128][d pitch 72]; wave w owns pr in [w*32, w*32+32)
    short* pb = partial + (size_t)blockIdx.x * PART_SZ + w * 32 * PART_P;
#pragma unroll
    for (int i = 0; i < 9; ++i) {
      int e = i * 64 + lane;  // 576 s4v = 32 rows x 18 s4v (pitch 72 = 18*4)
      *(s4v*)(pb + e * 4) = *(const s4v*)(kw + e * 4);
    }
  } else {
    // fallback: f32 atomics into kvacc[b][m][d] pitch 72 (global m order)
    float* pb = kvacc + (size_t)b * ACC_SZ;
#pragma unroll
    for (int mt = 0; mt < 2; ++mt) {
#pragma unroll
      for (int reg = 0; reg < 4; ++reg) {
        int m = mh * 128 + w * 32 + mt * 16 + q * 4 + reg;
#pragma unroll
        for (int n = 0; n < 4; ++n)
          atomicAdd(pb + (size_t)m * PART_P + n * 16 + r15, acc[mt][n][reg]);
        if (r15 == 0) atomicAdd(pb + (size_t)m * PART_P + 64, acc[mt][4][reg]);
      }
    }
  }
}

// ---- Kernel finalize: reduce bf16 partials -> kvfrag (B-fragment order) ----
// partial layout [blk][pr=128][d pitch 72]; blk = (b*64+scb)*2 + mh;
// m global = mh*128 + pr. Sum over 64 scb (stride 2*PART_SZ).
// kvfrag[b][fid=ks*5+n][lane][j]: lane holds B[k=ks*32+(lane>>4)*8+j][d=n*16+(lane&15)]
__global__ __launch_bounds__(256) void kv_finalize(
    const short* __restrict__ partial, const float* __restrict__ kvacc,
    short* __restrict__ kvfrag, int use_partial) {
  int i = blockIdx.x * 256 + threadIdx.x;  // 163840 outputs: (b, m=0..255, d=0..79)
  int b = i / 20480;
  int rem = i - b * 20480;
  int m = rem / 80;
  int d = rem - m * 80;
  float s = 0.f;
  if (d < 65) {
    if (use_partial) {
      int mh = m >> 7, pr = m & 127;
      const short* p = partial + ((size_t)(b * 128 + mh)) * PART_SZ + pr * PART_P + d;
#pragma unroll 8
      for (int c = 0; c < 64; ++c) s += bf16_to_f(p[(size_t)c * 2 * PART_SZ]);
    } else {
      s = kvacc[(size_t)b * ACC_SZ + (size_t)m * PART_P + d];
    }
  }
  int ks = m >> 5, qq = (m >> 3) & 3, j = m & 7;
  int n = d >> 4, r = d & 15;
  int lane = qq * 16 + r;
  if (d < 80)
    kvfrag[(((size_t)b * 40 + ks * 5 + n) * 64 + lane) * 8 + j] = bf16_rne(s);
}

// ---- Kernel QKV: fused phi(q) + qkv GEMM + normalize ----
// grid 1024 = 8b x 128 t-chunks(64). qf is wave-private -> no barriers.
__global__ __launch_bounds__(256, 4) void qkv_fused(
    const float* __restrict__ query, const short* __restrict__ ohf,
    const short* __restrict__ olf, const short* __restrict__ kvfrag,
    float* __restrict__ out) {
  __shared__ __align__(16) short qf[64 * QF_P];  // [t][feat] bf16, 33792 B
  const int tid = threadIdx.x, lane = tid & 63, w = tid >> 6;
  const int b = blockIdx.x >> 7;
  const int t0 = (blockIdx.x & 127) * 64;
  const int q = lane >> 4, r15 = lane & 15;

  // phi(q), swapped operands: C row = omega-row, col = t -> packed s4v writes
  {
    PhiRows P;
    load_phi_rows(query + ((size_t)b * NT + t0 + w * 16) * 64, lane, P);
    const int t_loc = w * 16 + r15;
#pragma unroll
    for (int ft = 0; ft < 8; ++ft) {
      f4v c = phi_xw_tile_T(P, ohf, olf, ft, lane);
      s4v pk, nk;
#pragma unroll
      for (int reg = 0; reg < 4; ++reg) {
        float xw = c[reg];  // feature ft*16+q*4+reg for x-row r15 (own ss)
        pk[reg] = bf16_rne((__expf(xw - P.ss) + EPSF) * SCALE);
        nk[reg] = bf16_rne((__expf(-xw - P.ss) + EPSF) * SCALE);
      }
      *(s4v*)(qf + t_loc * QF_P + ft * 16 + q * 4) = pk;
      *(s4v*)(qf + t_loc * QF_P + 128 + ft * 16 + q * 4) = nk;
    }
  }
  // GEMM: wave w's A rows = its own 16 t-rows; B-frags straight from global (L2)
  f4v acc[5];
#pragma unroll
  for (int n = 0; n < 5; ++n) acc[n] = f4v{0.f, 0.f, 0.f, 0.f};
  const short* kvb = kvfrag + (size_t)b * 40 * 512;
#pragma unroll
  for (int ks = 0; ks < 8; ++ks) {
    s8v a = *(const s8v*)(qf + (w * 16 + r15) * QF_P + ks * 32 + q * 8);
#pragma unroll
    for (int n = 0; n < 5; ++n) {
      s8v bf = *(const s8v*)(kvb + ((size_t)(ks * 5 + n)) * 512 + lane * 8);
      acc[n] = mfma16(a, bf, acc[n]);
    }
  }
  // denominator: N-tile 4 col 0 (d=64) holds den for rows q*4+reg
  float den_r[4];
#pragma unroll
  for (int reg = 0; reg < 4; ++reg) den_r[reg] = __shfl(acc[4][reg], lane & 48, 64);
  // normalize + stage into this wave's own qf region (its A-reads are done)
  float* stg = (float*)(qf + w * 16 * QF_P);  // 16x68 f32 = 4352 B < 8448 B region
#pragma unroll
  for (int n = 0; n < 4; ++n)
#pragma unroll
    for (int reg = 0; reg < 4; ++reg) {
      int row = q * 4 + reg;
      int col = n * 16 + r15;
      stg[row * 68 + col] = acc[n][reg] / den_r[reg];
    }
  // coalesced copy out (wave-private)
  float* ob = out + ((size_t)b * NT + t0 + w * 16) * 64;
#pragma unroll
  for (int rr = 0; rr < 4; ++rr) {
    int row = rr * 4 + q;
    int c4 = r15 * 4;
    *(f4v*)(ob + row * 64 + c4) = *(const f4v*)(stg + row * 68 + c4);
  }
}

extern "C" void kernel_launch(void* const* d_in, const int* in_sizes, int n_in,
                              void* d_out, int out_size, void* d_ws, size_t ws_size,
                              hipStream_t stream) {
  const float* query = (const float*)d_in[0];  // [8][8192][64]
  const float* value = (const float*)d_in[1];  // [8][8192][64]
  const float* key   = (const float*)d_in[2];  // [8][8192][64]
  const float* omega = (const float*)d_in[3];  // [128][64]
  float* out = (float*)d_out;

  char* ws = (char*)d_ws;
  short* ohf = (short*)ws;                       // 16384 B (frag-ordered hi)
  short* olf = (short*)(ws + 16384);             // 16384 B (frag-ordered lo)
  short* kvfrag = (short*)(ws + 32768);          // 8*40*512*2 = 327680 B
  short* partial = (short*)(ws + 360448);        // 1024*9216*2 = 18874368 B
  float* kvacc = (float*)(ws + 360448);          // fallback: 8*18432*4 = 589824 B
  const size_t need_full = 360448 + (size_t)KV_GRID * PART_SZ * 2;  // ~19.2 MB
  const int use_partial = (ws_size >= need_full) ? 1 : 0;

  setup_omega<<<32, 256, 0, stream>>>(omega, ohf, olf);
  if (!use_partial) {
    hipMemsetAsync(kvacc, 0, (size_t)8 * ACC_SZ * 4, stream);  // atomic targets
  }
  kv_fused<<<KV_GRID, 256, 0, stream>>>(key, value, ohf, olf, partial, kvacc, use_partial);
  kv_finalize<<<640, 256, 0, stream>>>(partial, kvacc, kvfrag, use_partial);
  qkv_fused<<<1024, 256, 0, stream>>>(query, ohf, olf, kvfrag, out);
}

// Round 6
// 130.034 us; speedup vs baseline: 1.4992x; 1.4992x over previous
//
#include <hip/hip_runtime.h>

// LinearAttention (Performer/FAVOR+): B=8, T=S=8192, F=D=64, M=128 (2M=256 features)
// R12: fix the REPLICATED spill: bounds(256,4) => allocator targets 64 VGPR =>
// ~80MB/launch scratch traffic (R10: 64reg/115MB, R11: 64reg/100MB vs R0 at
// bounds(256,2): 128reg/20.5MB clean). launch_bounds doesn't create occupancy --
// grid and actual VGPR/LDS do. R2's 25us kv (acc[4][5], (256,2), 128reg) was
// grid-limited (512 = 2 blk/CU) while VGPR+LDS allowed 4.
//   => R12 = R9 geometry (grid 1024 = 8b x 128 chunks of 64 s; K/V read ONCE;
//      xw computed once, exp'd twice; acc[4][5]) + bounds(256,2) (no squeeze)
//      + unroll-2 rg loop to bound phi transients. 4 blk/CU from the grid.
// Predicted: VGPR>=96 (not 64), WRITE~38-40MB (spill gone), kv 12-18us,
// total 115-125us (floor ~110 given 2x41.5us harness fills).
//
// MFMA 16x16x32 bf16 layouts (measured, learn_hip m89/m91):
//   A-frag: lane holds A[m = lane&15][k = (lane>>4)*8 + j], j=0..7
//   B-frag: lane holds B[k = (lane>>4)*8 + j][n = lane&15]
//   C/D   : lane holds D[row = (lane>>4)*4 + reg][col = lane&15], reg=0..3

constexpr int NB = 8;
constexpr int NT = 8192;
constexpr float EPSF = 1e-9f;
constexpr float SCALE = 0.0625f;  // 1/sqrt(2*128)

typedef short s8v __attribute__((ext_vector_type(8)));
typedef short s4v __attribute__((ext_vector_type(4)));
typedef float f4v __attribute__((ext_vector_type(4)));

__device__ inline f4v mfma16(s8v a, s8v b, f4v c) {
  return __builtin_amdgcn_mfma_f32_16x16x32_bf16(a, b, c, 0, 0, 0);
}

__device__ inline short bf16_rne(float f) {
  unsigned u = __builtin_bit_cast(unsigned, f);
  u += 0x7fffu + ((u >> 16) & 1u);
  return (short)(u >> 16);
}
__device__ inline float bf16_to_f(short h) {
  unsigned u = ((unsigned)(unsigned short)h) << 16;
  return __builtin_bit_cast(float, u);
}

// ---- setup: split omega into bf16 hi/lo (Markidis 3-term split), stored in
// MFMA-FRAG ORDER: ohf[((ft*2 + h)*64 + lane)*8 + jj] = omega_hi[m][f] with
// m = ft*16 + (lane&15), f = h*32 + (lane>>4)*8 + jj. ----
__global__ void setup_omega(const float* __restrict__ omega,
                            short* __restrict__ ohf, short* __restrict__ olf) {
  int i = blockIdx.x * 256 + threadIdx.x;
  if (i >= 128 * 64) return;
  int jj = i & 7;
  int lane = (i >> 3) & 63;
  int h = (i >> 9) & 1;
  int ft = i >> 10;
  int m = ft * 16 + (lane & 15);
  int f = h * 32 + (lane >> 4) * 8 + jj;
  float wv = omega[m * 64 + f];
  short hh = bf16_rne(wv);
  ohf[i] = hh;
  olf[i] = bf16_rne(wv - bf16_to_f(hh));
}

// ---- shared phi helpers ----
struct PhiRows {
  s8v ah0, al0, ah1, al1;  // x fragments (hi/lo) for ksteps 0,1
  float ssr[4];            // |x_row|^2/2 for rows quad*4+reg (C-row indexed)
  float ss;                // |x_row|^2/2 for this lane's own row (lane&15)
};

__device__ inline void split8(f4v a, f4v b, s8v& h, s8v& l) {
  float v[8] = {a.x, a.y, a.z, a.w, b.x, b.y, b.z, b.w};
#pragma unroll
  for (int j = 0; j < 8; ++j) {
    short hh = bf16_rne(v[j]);
    h[j] = hh;
    l[j] = bf16_rne(v[j] - bf16_to_f(hh));
  }
}

__device__ inline void load_phi_rows(const float* __restrict__ xrow_base, int lane, PhiRows& P) {
  const int r = lane & 15, q = lane >> 4;
  const float* p = xrow_base + r * 64 + q * 8;
  f4v u0 = *(const f4v*)(p);
  f4v u1 = *(const f4v*)(p + 4);
  f4v u2 = *(const f4v*)(p + 32);
  f4v u3 = *(const f4v*)(p + 36);
  float ss = u0.x * u0.x + u0.y * u0.y + u0.z * u0.z + u0.w * u0.w
           + u1.x * u1.x + u1.y * u1.y + u1.z * u1.z + u1.w * u1.w
           + u2.x * u2.x + u2.y * u2.y + u2.z * u2.z + u2.w * u2.w
           + u3.x * u3.x + u3.y * u3.y + u3.z * u3.z + u3.w * u3.w;
  ss += __shfl_xor(ss, 16, 64);
  ss += __shfl_xor(ss, 32, 64);
  ss *= 0.5f;
  P.ss = ss;
#pragma unroll
  for (int reg = 0; reg < 4; ++reg) P.ssr[reg] = __shfl(ss, q * 4 + reg, 64);
  split8(u0, u1, P.ah0, P.al0);
  split8(u2, u3, P.ah1, P.al1);
}

// xw C-tile, A = x rows (C: row = x-row q*4+reg, col = omega-row lane&15).
__device__ inline f4v phi_xw_tile(const PhiRows& P, const short* __restrict__ ohf,
                                  const short* __restrict__ olf, int ft, int lane) {
  const int o0 = ft * 1024 + lane * 8;
  s8v bh0 = *(const s8v*)(ohf + o0);
  s8v bh1 = *(const s8v*)(ohf + o0 + 512);
  s8v bl0 = *(const s8v*)(olf + o0);
  s8v bl1 = *(const s8v*)(olf + o0 + 512);
  f4v c = {0.f, 0.f, 0.f, 0.f};
  c = mfma16(P.ah0, bh0, c);
  c = mfma16(P.ah1, bh1, c);
  c = mfma16(P.al0, bh0, c);
  c = mfma16(P.al1, bh1, c);
  c = mfma16(P.ah0, bl0, c);
  c = mfma16(P.ah1, bl1, c);
  return c;
}

// xw C-tile, swapped: A = omega rows (C: row = omega-row q*4+reg, col = x-row lane&15).
__device__ inline f4v phi_xw_tile_T(const PhiRows& P, const short* __restrict__ ohf,
                                    const short* __restrict__ olf, int ft, int lane) {
  const int o0 = ft * 1024 + lane * 8;
  s8v ah0 = *(const s8v*)(ohf + o0);
  s8v ah1 = *(const s8v*)(ohf + o0 + 512);
  s8v al0 = *(const s8v*)(olf + o0);
  s8v al1 = *(const s8v*)(olf + o0 + 512);
  f4v c = {0.f, 0.f, 0.f, 0.f};
  c = mfma16(ah0, P.ah0, c);
  c = mfma16(ah1, P.ah1, c);
  c = mfma16(al0, P.ah0, c);
  c = mfma16(al1, P.ah1, c);
  c = mfma16(ah0, P.al0, c);
  c = mfma16(ah1, P.al1, c);
  return c;
}

constexpr int KF_P = 72;               // kft pitch in shorts (also partial row pitch)
constexpr int QF_P = 264;              // qf pitch (shorts): 256 + 8 pad
constexpr int PART_P = 72;             // partial pitch: [pr=256][d pitch 72] shorts
constexpr int PART_SZ = 256 * PART_P;  // 18432 shorts per block tile
constexpr int KV_GRID = 1024;          // 8 batches x 128 s-chunks of 64

// ---- Kernel KV: fused phi(k) + kv GEMM; grid supplies 4 blk/CU, no reg squeeze ----
// grid 1024 = 8b x 128 s-chunks(64). Wave w owns omega tiles {2w, 2w+1}, BOTH
// signs -> 64 m-rows: m_loc 0..31 = pos (w*32+ml), 32..63 = neg (128+w*32+ml-32).
// Wave-private kft quarter; zero barriers. bounds(256,2): 256-reg budget ->
// allocator lands ~128 (R0-measured), no spill; runtime occupancy comes from
// grid(1024)/LDS(36.9KB)/VGPR(~128) all allowing 4 blocks/CU.
__global__ __launch_bounds__(256, 2) void kv_fused(
    const float* __restrict__ key, const float* __restrict__ value,
    const short* __restrict__ ohf, const short* __restrict__ olf,
    short* __restrict__ partial, float* __restrict__ kvacc, int use_partial) {
  __shared__ short kft[4 * 64 * KF_P];  // 36864 B, wave-private quarters
  const int tid = threadIdx.x, lane = tid & 63, w = tid >> 6;
  const int b = blockIdx.x >> 7;
  const int s0 = (blockIdx.x & 127) * 64;
  const int q = lane >> 4, r15 = lane & 15;
  short* kw = kft + w * 64 * KF_P;

  // constant [v|1] ones-column fragment: B[k][n=64..79] = (n==64) ? 1.0 : 0
  s8v vone;
#pragma unroll
  for (int jj = 0; jj < 8; ++jj) vone[jj] = (r15 == 0) ? (short)0x3F80 : (short)0;

  // phi(k): 4 row-groups of 16 s each; this wave's 2 omega tiles, both signs.
  // unroll 2 bounds the key-load transients (keep live-set under ~128).
#pragma unroll 2
  for (int rg = 0; rg < 4; ++rg) {
    PhiRows P;
    load_phi_rows(key + ((size_t)b * NT + s0 + rg * 16) * 64, lane, P);
#pragma unroll
    for (int ftl = 0; ftl < 2; ++ftl) {
      f4v c = phi_xw_tile(P, ohf, olf, w * 2 + ftl, lane);
      s4v pk, nk;
#pragma unroll
      for (int reg = 0; reg < 4; ++reg) {
        float xw = c[reg];  // x-row (rg*16+q*4+reg), omega-row (w*2+ftl)*16+r15
        pk[reg] = bf16_rne((__expf(xw - P.ssr[reg]) + EPSF) * SCALE);
        nk[reg] = bf16_rne((__expf(-xw - P.ssr[reg]) + EPSF) * SCALE);
      }
      // kft row = m_loc; col = s-local. s4v spans 4 consecutive s.
      *(s4v*)(kw + (ftl * 16 + r15) * KF_P + rg * 16 + q * 4) = pk;
      *(s4v*)(kw + (32 + ftl * 16 + r15) * KF_P + rg * 16 + q * 4) = nk;
    }
  }
  // GEMM over this chunk's 64 s; B-frags from global value (L1-resident 16KB)
  f4v acc[4][5];
#pragma unroll
  for (int mt = 0; mt < 4; ++mt)
#pragma unroll
    for (int n = 0; n < 5; ++n) acc[mt][n] = f4v{0.f, 0.f, 0.f, 0.f};
  const float* vb = value + ((size_t)b * NT + s0) * 64;
#pragma unroll
  for (int ks = 0; ks < 2; ++ks) {
    s8v bf[5];
#pragma unroll
    for (int n = 0; n < 4; ++n) {
#pragma unroll
      for (int jj = 0; jj < 8; ++jj)
        bf[n][jj] = bf16_rne(vb[(ks * 32 + q * 8 + jj) * 64 + n * 16 + r15]);
    }
    bf[4] = vone;
#pragma unroll
    for (int mt = 0; mt < 4; ++mt) {
      s8v a = *(const s8v*)(kw + (mt * 16 + r15) * KF_P + ks * 32 + q * 8);
#pragma unroll
      for (int n = 0; n < 5; ++n) acc[mt][n] = mfma16(a, bf[n], acc[mt][n]);
    }
  }
  // ---- epilogue ----
  // C element (mt,n,reg): m_loc = mt*16+q*4+reg, d = n*16+r15.
  if (use_partial) {
    // Stage 64x65 tile into idle kw quarter [m_loc][d] pitch 72, then
    // linear-copy 576 s8v (16B fully coalesced).
#pragma unroll
    for (int mt = 0; mt < 4; ++mt) {
#pragma unroll
      for (int n = 0; n < 4; ++n) {
#pragma unroll
        for (int reg = 0; reg < 4; ++reg)
          kw[(mt * 16 + q * 4 + reg) * KF_P + n * 16 + r15] = bf16_rne(acc[mt][n][reg]);
      }
      if (r15 == 0) {  // n=4 tile: only d=64 is real
#pragma unroll
        for (int reg = 0; reg < 4; ++reg)
          kw[(mt * 16 + q * 4 + reg) * KF_P + 64] = bf16_rne(acc[mt][4][reg]);
      }
    }
    // partial[block][pr=256][d pitch 72]; wave w owns pr in [w*64, w*64+64)
    short* pb = partial + (size_t)blockIdx.x * PART_SZ + w * 64 * PART_P;
#pragma unroll
    for (int i = 0; i < 9; ++i) {
      int e = i * 64 + lane;  // 576 s8v = 64 rows x 9 s8v (pitch 72 = 9*8)
      *(s8v*)(pb + e * 8) = *(const s8v*)(kw + e * 8);
    }
  } else {
    // fallback: f32 atomics into kvacc[b][m][d] pitch 72 (global m order)
    float* pb = kvacc + (size_t)b * PART_SZ;
#pragma unroll
    for (int mt = 0; mt < 4; ++mt) {
#pragma unroll
      for (int reg = 0; reg < 4; ++reg) {
        int ml = mt * 16 + q * 4 + reg;
        int m = (ml < 32) ? (w * 32 + ml) : (128 + w * 32 + (ml - 32));
#pragma unroll
        for (int n = 0; n < 4; ++n)
          atomicAdd(pb + (size_t)m * PART_P + n * 16 + r15, acc[mt][n][reg]);
        if (r15 == 0) atomicAdd(pb + (size_t)m * PART_P + 64, acc[mt][4][reg]);
      }
    }
  }
}

// ---- Kernel finalize: reduce bf16 partials -> kvfrag (B-fragment order) ----
// partial layout [blk][pr][d] pitch 72 with pr = w*64 + ml, where
//   m < 128 (pos): w = m>>5, ml = m&31;  m >= 128 (neg): w = (m-128)>>5, ml = 32+((m-128)&31).
// kvfrag[b][fid=ks*5+n][lane][j]: lane holds B[k=ks*32+(lane>>4)*8+j][d=n*16+(lane&15)]
__global__ __launch_bounds__(256) void kv_finalize(
    const short* __restrict__ partial, const float* __restrict__ kvacc,
    short* __restrict__ kvfrag, int use_partial) {
  int i = blockIdx.x * 256 + threadIdx.x;  // 163840 outputs: (b, m=0..255, d=0..79)
  int b = i / 20480;
  int rem = i - b * 20480;
  int m = rem / 80;
  int d = rem - m * 80;
  float s = 0.f;
  if (d < 65) {
    if (use_partial) {
      int w_, ml;
      if (m < 128) { w_ = m >> 5; ml = m & 31; }
      else { int mm = m - 128; w_ = mm >> 5; ml = 32 + (mm & 31); }
      int pr = w_ * 64 + ml;
      const short* p = partial + (size_t)(b * 128) * PART_SZ + pr * PART_P + d;
#pragma unroll 8
      for (int c = 0; c < 128; ++c) s += bf16_to_f(p[(size_t)c * PART_SZ]);
    } else {
      s = kvacc[(size_t)b * PART_SZ + (size_t)m * PART_P + d];
    }
  }
  int ks = m >> 5, qq = (m >> 3) & 3, j = m & 7;
  int n = d >> 4, r = d & 15;
  int lane = qq * 16 + r;
  if (d < 80)
    kvfrag[(((size_t)b * 40 + ks * 5 + n) * 64 + lane) * 8 + j] = bf16_rne(s);
}

// ---- Kernel QKV: fused phi(q) + qkv GEMM + normalize ----
// grid 1024 = 8b x 128 t-chunks(64). qf is wave-private -> no barriers.
__global__ __launch_bounds__(256, 4) void qkv_fused(
    const float* __restrict__ query, const short* __restrict__ ohf,
    const short* __restrict__ olf, const short* __restrict__ kvfrag,
    float* __restrict__ out) {
  __shared__ __align__(16) short qf[64 * QF_P];  // [t][feat] bf16, 33792 B
  const int tid = threadIdx.x, lane = tid & 63, w = tid >> 6;
  const int b = blockIdx.x >> 7;
  const int t0 = (blockIdx.x & 127) * 64;
  const int q = lane >> 4, r15 = lane & 15;

  // phi(q), swapped operands: C row = omega-row, col = t -> packed s4v writes
  {
    PhiRows P;
    load_phi_rows(query + ((size_t)b * NT + t0 + w * 16) * 64, lane, P);
    const int t_loc = w * 16 + r15;
#pragma unroll
    for (int ft = 0; ft < 8; ++ft) {
      f4v c = phi_xw_tile_T(P, ohf, olf, ft, lane);
      s4v pk, nk;
#pragma unroll
      for (int reg = 0; reg < 4; ++reg) {
        float xw = c[reg];  // feature ft*16+q*4+reg for x-row r15 (own ss)
        pk[reg] = bf16_rne((__expf(xw - P.ss) + EPSF) * SCALE);
        nk[reg] = bf16_rne((__expf(-xw - P.ss) + EPSF) * SCALE);
      }
      *(s4v*)(qf + t_loc * QF_P + ft * 16 + q * 4) = pk;
      *(s4v*)(qf + t_loc * QF_P + 128 + ft * 16 + q * 4) = nk;
    }
  }
  // GEMM: wave w's A rows = its own 16 t-rows; B-frags straight from global (L2)
  f4v acc[5];
#pragma unroll
  for (int n = 0; n < 5; ++n) acc[n] = f4v{0.f, 0.f, 0.f, 0.f};
  const short* kvb = kvfrag + (size_t)b * 40 * 512;
#pragma unroll
  for (int ks = 0; ks < 8; ++ks) {
    s8v a = *(const s8v*)(qf + (w * 16 + r15) * QF_P + ks * 32 + q * 8);
#pragma unroll
    for (int n = 0; n < 5; ++n) {
      s8v bf = *(const s8v*)(kvb + ((size_t)(ks * 5 + n)) * 512 + lane * 8);
      acc[n] = mfma16(a, bf, acc[n]);
    }
  }
  // denominator: N-tile 4 col 0 (d=64) holds den for rows q*4+reg
  float den_r[4];
#pragma unroll
  for (int reg = 0; reg < 4; ++reg) den_r[reg] = __shfl(acc[4][reg], lane & 48, 64);
  // normalize + stage into this wave's own qf region (its A-reads are done)
  float* stg = (float*)(qf + w * 16 * QF_P);  // 16x68 f32 = 4352 B < 8448 B region
#pragma unroll
  for (int n = 0; n < 4; ++n)
#pragma unroll
    for (int reg = 0; reg < 4; ++reg) {
      int row = q * 4 + reg;
      int col = n * 16 + r15;
      stg[row * 68 + col] = acc[n][reg] / den_r[reg];
    }
  // coalesced copy out (wave-private)
  float* ob = out + ((size_t)b * NT + t0 + w * 16) * 64;
#pragma unroll
  for (int rr = 0; rr < 4; ++rr) {
    int row = rr * 4 + q;
    int c4 = r15 * 4;
    *(f4v*)(ob + row * 64 + c4) = *(const f4v*)(stg + row * 68 + c4);
  }
}

extern "C" void kernel_launch(void* const* d_in, const int* in_sizes, int n_in,
                              void* d_out, int out_size, void* d_ws, size_t ws_size,
                              hipStream_t stream) {
  const float* query = (const float*)d_in[0];  // [8][8192][64]
  const float* value = (const float*)d_in[1];  // [8][8192][64]
  const float* key   = (const float*)d_in[2];  // [8][8192][64]
  const float* omega = (const float*)d_in[3];  // [128][64]
  float* out = (float*)d_out;

  char* ws = (char*)d_ws;
  short* ohf = (short*)ws;                       // 16384 B (frag-ordered hi)
  short* olf = (short*)(ws + 16384);             // 16384 B (frag-ordered lo)
  short* kvfrag = (short*)(ws + 32768);          // 8*40*512*2 = 327680 B
  short* partial = (short*)(ws + 360448);        // 1024*18432*2 = 37748736 B
  float* kvacc = (float*)(ws + 360448);          // fallback: 8*18432*4 = 589824 B
  const size_t need_full = 360448 + (size_t)KV_GRID * PART_SZ * 2;  // ~38.1 MB
  const int use_partial = (ws_size >= need_full) ? 1 : 0;

  setup_omega<<<32, 256, 0, stream>>>(omega, ohf, olf);
  if (!use_partial) {
    hipMemsetAsync(kvacc, 0, (size_t)8 * PART_SZ * 4, stream);  // atomic targets
  }
  kv_fused<<<KV_GRID, 256, 0, stream>>>(key, value, ohf, olf, partial, kvacc, use_partial);
  kv_finalize<<<640, 256, 0, stream>>>(partial, kvacc, kvfrag, use_partial);
  qkv_fused<<<1024, 256, 0, stream>>>(query, ohf, olf, kvfrag, out);
}